// Round 5
// baseline (205.049 us; speedup 1.0000x reference)
//
#include <hip/hip_runtime.h>

// Problem constants: B=8, S=512, D_MODEL=1024, H=16, dh=64, SCALE=8.
typedef unsigned short u16;
typedef __bf16 bf16_t;
typedef bf16_t bf16x8 __attribute__((ext_vector_type(8)));
typedef float f32x4 __attribute__((ext_vector_type(4)));
typedef u16 u16x8 __attribute__((ext_vector_type(8)));
typedef u16 u16x4 __attribute__((ext_vector_type(4)));

__device__ __forceinline__ u16 f2b(float f) {
    unsigned int u = __float_as_uint(f);
    u += 0x7fffu + ((u >> 16) & 1u);   // RNE
    return (u16)(u >> 16);
}

__device__ __forceinline__ f32x4 mfma16(u16x8 a, u16x8 b, f32x4 c) {
    return __builtin_amdgcn_mfma_f32_16x16x32_bf16(
        __builtin_bit_cast(bf16x8, a), __builtin_bit_cast(bf16x8, b), c, 0, 0, 0);
}

#define GLDS16(gp, lp)                                                          \
    __builtin_amdgcn_global_load_lds(                                           \
        (const __attribute__((address_space(1))) void*)(gp),                    \
        (__attribute__((address_space(3))) void*)(lp), 16, 0, 0)

// ---------------- fp32 -> bf16 convert (x | Wqkv | fc_w fused) ---------------
__global__ __launch_bounds__(256) void cvt3_kernel(const float* __restrict__ s0,
                                                   const float* __restrict__ s1,
                                                   const float* __restrict__ s2,
                                                   u16* __restrict__ d0,
                                                   u16* __restrict__ d1,
                                                   u16* __restrict__ d2) {
    int i = (blockIdx.x * 256 + threadIdx.x) * 4;   // block-uniform ranges
    const float* src; u16* dst;
    if (i < 4194304)       { src = s0;           dst = d0;           }
    else if (i < 8388608)  { src = s1 - 4194304; dst = d1 - 4194304; }
    else                   { src = s2 - 8388608; dst = d2 - 8388608; }
    float4 f = *(const float4*)(src + i);
    u16x4 o = { f2b(f.x), f2b(f.y), f2b(f.z), f2b(f.w) };
    *(u16x4*)(dst + i) = o;
}

// ---------------- NT bf16 GEMM, K=1024, double-buffered LDS ------------------
// MODE 0 (MT=128): writes q/k1/k2 in per-(b,h) fragment-major layout
//   [bh][tile16][khalf][lane=quad*16+lr][8]   (lane's exact MFMA 16B frag)
// and v in PV-frag-major layout [bh][ot][cc][lane][8].
// MODE 1 (MT=64):  Cf[m][n] = acc + bias[n]  (fp32, ld 1024)
template <int MT, int MODE>
__global__ __launch_bounds__(256) void gemm_bt(
    const u16* __restrict__ A, const u16* __restrict__ Bw,
    u16* __restrict__ Qf, u16* __restrict__ K1f,
    u16* __restrict__ K2f, u16* __restrict__ Vf,
    float* __restrict__ Cf, const float* __restrict__ biasp)
{
    constexpr int K = 1024;
    constexpr int MF = MT / 32;            // A-frags per wave (4 or 2)
    __shared__ u16 As[2][MT * 32];
    __shared__ u16 Bs[2][128 * 32];
    const int t = threadIdx.x;
    const int lane = t & 63;
    const int w = t >> 6;
    const int wm = w >> 1, wn = w & 1;
    const int lr = lane & 15, quad = lane >> 4;
    const int tileM = blockIdx.y * MT, tileN = blockIdx.x * 128;

    f32x4 acc[MF][4] = {};

    const u16* Ag = A + (size_t)(tileM + (t >> 2)) * K + (t & 3) * 8;
    const u16* Bg = Bw + (size_t)(tileN + (t >> 2)) * K + (t & 3) * 8;

#define STAGE(kk, bufi)                                                         \
    do {                                                                        \
        GLDS16(Ag + (kk), &As[bufi][t * 8]);                                    \
        if (MT == 128) GLDS16(Ag + (kk) + 64 * K, &As[bufi][t * 8 + 2048]);     \
        GLDS16(Bg + (kk), &Bs[bufi][t * 8]);                                    \
        GLDS16(Bg + (kk) + 64 * K, &Bs[bufi][t * 8 + 2048]);                    \
    } while (0)

    STAGE(0, 0);
    __syncthreads();

#pragma unroll 2
    for (int kk = 0; kk < K; kk += 32) {
        const int cur = (kk >> 5) & 1;
        if (kk + 32 < K) STAGE(kk + 32, cur ^ 1);   // prefetch next tile

        u16x8 af[MF], bf[4];
#pragma unroll
        for (int i = 0; i < MF; ++i)
            af[i] = *(const u16x8*)(&As[cur][(wm * (MT / 2) + i * 16 + lr) * 32 + quad * 8]);
#pragma unroll
        for (int i = 0; i < 4; ++i)
            bf[i] = *(const u16x8*)(&Bs[cur][(wn * 64 + i * 16 + lr) * 32 + quad * 8]);
#pragma unroll
        for (int mi = 0; mi < MF; ++mi)
#pragma unroll
            for (int ni = 0; ni < 4; ++ni)
                acc[mi][ni] = mfma16(af[mi], bf[ni], acc[mi][ni]);

        __syncthreads();   // drains prefetch vmcnt + protects buffer reuse
    }
#undef STAGE

    if (MODE == 0) {
#pragma unroll
        for (int mi = 0; mi < MF; ++mi)
#pragma unroll
            for (int ni = 0; ni < 4; ++ni) {
                int n = tileN + wn * 64 + ni * 16 + lr;
                int kv = n >> 10;                 // 0=q 1=k1 2=k2 3=v
                int h = (n >> 6) & 15, d = n & 63;
#pragma unroll
                for (int r = 0; r < 4; ++r) {
                    int m = tileM + wm * (MT / 2) + mi * 16 + quad * 4 + r;
                    int s = m & 511, bh = ((m >> 9) << 4) + h;
                    u16 v = f2b(acc[mi][ni][r]);
                    if (kv < 3) {
                        // frag-major: [bh][s>>4][d>>5][((d>>3)&3)*16+(s&15)][d&7]
                        u16* base = (kv == 0) ? Qf : (kv == 1) ? K1f : K2f;
                        size_t idx = ((size_t)((bh * 32 + (s >> 4)) * 2 + (d >> 5))) * 512
                                   + (((d >> 3) & 3) * 16 + (s & 15)) * 8 + (d & 7);
                        base[idx] = v;
                    } else {
                        // v frag-major: [bh][d>>4][s>>5][((s>>3)&3)*16+(d&15)][s&7]
                        size_t idx = ((size_t)((bh * 4 + (d >> 4)) * 16 + (s >> 5))) * 512
                                   + (((s >> 3) & 3) * 16 + (d & 15)) * 8 + (s & 7);
                        Vf[idx] = v;
                    }
                }
            }
    } else {
#pragma unroll
        for (int mi = 0; mi < MF; ++mi)
#pragma unroll
            for (int ni = 0; ni < 4; ++ni) {
                int n = tileN + wn * 64 + ni * 16 + lr;
                float bv = biasp[n];
#pragma unroll
                for (int r = 0; r < 4; ++r) {
                    int m = tileM + wm * (MT / 2) + mi * 16 + quad * 4 + r;
                    Cf[(size_t)m * 1024 + n] = acc[mi][ni][r] + bv;
                }
            }
    }
}

// ---------------- attention: barrier-free, register-direct frag loads --------
// Grid 512 linear: bh = blk&127 (same-bh blocks stride 128 = 0 mod 8 -> same
// XCD for L2 locality), qt = blk>>7 (0..3). Wave w owns 32 q-rows
// [qt*128 + w*32, +32) x all 512 keys. Frag-major K/V in global means each
// frag load is ONE coalesced global_load_dwordx4 (base + lane*16B) -> no LDS
// staging, no __syncthreads; compiler pipelines loads across chunks with
// precise vmcnt. Softmax: fixed max-shift (scores bounded), one final 16-lane
// reduction. P C->A transpose via per-wave swizzled LDS (lgkmcnt only).
__global__ __launch_bounds__(256) void attn_kernel(
    const u16* __restrict__ qfm, const u16* __restrict__ k1fm,
    const u16* __restrict__ k2fm, const u16* __restrict__ vfm,
    const int* __restrict__ maskp, const int* __restrict__ qmaskp,
    const float* __restrict__ shiftp, const float* __restrict__ biasp,
    u16* __restrict__ ao)
{
    __shared__ u16 Pw[4][2][512];        // per-wave, per-row-group swizzled P

    const int bh = blockIdx.x & 127, qt = blockIdx.x >> 7;
    const int b = bh >> 4, h = bh & 15;
    const int t = threadIdx.x, lane = t & 63, w = t >> 6;
    const int lr = lane & 15, quad = lane >> 4;
    const float shiftv = shiftp[0], biasv = biasp[0];

    const int qbase = qt * 128 + w * 32;    // wave's first q row
    const int m16 = qbase >> 4;             // first 16-row group index

    // Q A-frags: [g][kh], each = one coalesced 16B/lane load
    const u16* qb = qfm + ((size_t)(bh * 32 + m16) * 2) * 512 + lane * 8;
    u16x8 qa[2][2];
    qa[0][0] = *(const u16x8*)(qb);
    qa[0][1] = *(const u16x8*)(qb + 512);
    qa[1][0] = *(const u16x8*)(qb + 1024);
    qa[1][1] = *(const u16x8*)(qb + 1536);

    int qmr[2][4]; float rowf[2][4];
#pragma unroll
    for (int g = 0; g < 2; ++g)
#pragma unroll
        for (int r = 0; r < 4; ++r) {
            int m = qbase + g * 16 + quad * 4 + r;
            qmr[g][r] = qmaskp[b * 512 + m];
            rowf[g][r] = (float)m;
        }

    f32x4 o[2][4] = {};
    float lsum[2][4] = {};

    u16* pb[2] = { &Pw[w][0][0], &Pw[w][1][0] };
    const int wa0 = quad * 128 + (((lr >> 3) ^ quad) * 8) + (lr & 7);
    const int wa1 = quad * 128 + (((2 | (lr >> 3)) ^ quad) * 8) + (lr & 7);
    const int ra = lr * 32 + ((quad ^ (lr >> 2)) * 8);

    const u16* k1b = k1fm + (size_t)bh * 32768 + lane * 8;
    const u16* k2b = k2fm + (size_t)bh * 32768 + lane * 8;
    const u16* vb  = vfm  + (size_t)bh * 32768 + lane * 8;
    const int* qmb = qmaskp + b * 512;
    const int* kmb = maskp + b * 512;

#pragma unroll 2
    for (int cc = 0; cc < 16; ++cc) {
        // K frags: [k1/k2][t-group][kh] — 8 coalesced 16B/lane loads
        const u16* kc1 = k1b + cc * 2048;
        const u16* kc2 = k2b + cc * 2048;
        u16x8 k1f_[2][2], k2f_[2][2];
        k1f_[0][0] = *(const u16x8*)(kc1);
        k1f_[0][1] = *(const u16x8*)(kc1 + 512);
        k1f_[1][0] = *(const u16x8*)(kc1 + 1024);
        k1f_[1][1] = *(const u16x8*)(kc1 + 1536);
        k2f_[0][0] = *(const u16x8*)(kc2);
        k2f_[0][1] = *(const u16x8*)(kc2 + 512);
        k2f_[1][0] = *(const u16x8*)(kc2 + 1024);
        k2f_[1][1] = *(const u16x8*)(kc2 + 1536);
        // V frags: [ot] — 4 coalesced loads
        u16x8 vf_[4];
#pragma unroll
        for (int ot = 0; ot < 4; ++ot)
            vf_[ot] = *(const u16x8*)(vb + (size_t)(ot * 16 + cc) * 512);

        f32x4 z = {0.f, 0.f, 0.f, 0.f};
        f32x4 s1[2][2], s2[2][2];
#pragma unroll
        for (int g = 0; g < 2; ++g)
#pragma unroll
            for (int tg = 0; tg < 2; ++tg) {
                s1[g][tg] = mfma16(qa[g][1], k1f_[tg][1], mfma16(qa[g][0], k1f_[tg][0], z));
                s2[g][tg] = mfma16(qa[g][1], k2f_[tg][1], mfma16(qa[g][0], k2f_[tg][0], z));
            }

        const int col0 = cc * 32 + lr, col1 = col0 + 16;
        const int qmc0 = qmb[col0], qmc1 = qmb[col1];
        const float ka0 = (kmb[col0] ? 0.f : -1e30f) - 10.0f;   // mask + max-shift
        const float ka1 = (kmb[col1] ? 0.f : -1e30f) - 10.0f;
        const float colf0 = (float)col0, colf1 = (float)col1;

#pragma unroll
        for (int g = 0; g < 2; ++g) {
#pragma unroll
            for (int r = 0; r < 4; ++r) {
                float d0 = rowf[g][r] - colf0;
                float d1 = rowf[g][r] - colf1;
                float sel0 = (qmr[g][r] == qmc0) ? s1[g][0][r] : s2[g][0][r];
                float sel1 = (qmr[g][r] == qmc1) ? s1[g][1][r] : s2[g][1][r];
                float v0 = fmaf(sel0, 0.125f, -fmaf(shiftv * d0, d0, biasv)) + ka0;
                float v1 = fmaf(sel1, 0.125f, -fmaf(shiftv * d1, d1, biasv)) + ka1;
                float p0 = __expf(v0);
                float p1 = __expf(v1);
                lsum[g][r] += p0 + p1;
                pb[g][wa0 + r * 32] = f2b(p0);
                pb[g][wa1 + r * 32] = f2b(p1);
            }
        }
#pragma unroll
        for (int g = 0; g < 2; ++g) {
            u16x8 af = *(const u16x8*)(pb[g] + ra);   // same-wave RAW; lgkmcnt
#pragma unroll
            for (int ot = 0; ot < 4; ++ot)
                o[g][ot] = mfma16(af, vf_[ot], o[g][ot]);
        }
    }

    // epilogue: finish row sums across the 16 lr lanes, normalize, store
#pragma unroll
    for (int g = 0; g < 2; ++g)
#pragma unroll
        for (int r = 0; r < 4; ++r) {
            float s = lsum[g][r];
#pragma unroll
            for (int m = 1; m < 16; m <<= 1) s += __shfl_xor(s, m);
            float inv = 1.0f / s;
            int grow = b * 512 + qbase + g * 16 + quad * 4 + r;
            u16* orow = ao + (size_t)grow * 1024 + h * 64 + lr;
            orow[0]  = f2b(o[g][0][r] * inv);
            orow[16] = f2b(o[g][1][r] * inv);
            orow[32] = f2b(o[g][2][r] * inv);
            orow[48] = f2b(o[g][3][r] * inv);
        }
}

extern "C" void kernel_launch(void* const* d_in, const int* in_sizes, int n_in,
                              void* d_out, int out_size, void* d_ws, size_t ws_size,
                              hipStream_t stream) {
    (void)in_sizes; (void)n_in; (void)out_size; (void)ws_size;
    const float* x      = (const float*)d_in[0];
    const int*   maskp  = (const int*)d_in[1];
    const int*   qmaskp = (const int*)d_in[2];
    const float* Wqkv   = (const float*)d_in[3];
    const float* fc_w   = (const float*)d_in[4];
    const float* fc_b   = (const float*)d_in[5];
    const float* shiftp = (const float*)d_in[6];
    const float* biasp  = (const float*)d_in[7];
    float* out = (float*)d_out;

    char* ws = (char*)d_ws;
    u16* xb   = (u16*)(ws);                      //  8 MB: x bf16 [4096,1024]
    u16* wb   = (u16*)(ws + (8u << 20));         //  8 MB: Wqkv bf16 [4096,1024]
    u16* fwb  = (u16*)(ws + (16u << 20));        //  2 MB: fc_w bf16 [1024,1024]
    u16* qfm  = (u16*)(ws + (18u << 20));        //  8 MB: q frag-major
    u16* k1fm = (u16*)(ws + (26u << 20));        //  8 MB: k1 frag-major
    u16* k2fm = (u16*)(ws + (34u << 20));        //  8 MB: k2 frag-major
    u16* vfm  = (u16*)(ws + (42u << 20));        //  8 MB: v frag-major
    u16* aob  = (u16*)(ws + (50u << 20));        //  8 MB: attn out bf16 [4096,1024]

    cvt3_kernel<<<9216, 256, 0, stream>>>(x, Wqkv, fc_w, xb, wb, fwb);
    gemm_bt<128, 0><<<dim3(32, 32), 256, 0, stream>>>(xb, wb, qfm, k1fm, k2fm, vfm,
                                                      nullptr, nullptr);
    attn_kernel<<<512, 256, 0, stream>>>(qfm, k1fm, k2fm, vfm, maskp, qmaskp,
                                         shiftp, biasp, aob);
    gemm_bt<64, 1><<<dim3(8, 64), 256, 0, stream>>>(aob, fwb, nullptr, nullptr,
                                                    nullptr, nullptr, out, fc_b);
}

// Round 6
// 204.711 us; speedup vs baseline: 1.0017x; 1.0017x over previous
//
#include <hip/hip_runtime.h>

// Problem constants: B=8, S=512, D_MODEL=1024, H=16, dh=64, SCALE=8.
typedef unsigned short u16;
typedef __bf16 bf16_t;
typedef bf16_t bf16x8 __attribute__((ext_vector_type(8)));
typedef float f32x4 __attribute__((ext_vector_type(4)));
typedef u16 u16x8 __attribute__((ext_vector_type(8)));
typedef u16 u16x4 __attribute__((ext_vector_type(4)));

__device__ __forceinline__ u16 f2b(float f) {
    unsigned int u = __float_as_uint(f);
    u += 0x7fffu + ((u >> 16) & 1u);   // RNE
    return (u16)(u >> 16);
}
__device__ __forceinline__ unsigned int pk2(float a, float b) {
    return (unsigned int)f2b(a) | ((unsigned int)f2b(b) << 16);
}

__device__ __forceinline__ f32x4 mfma16(u16x8 a, u16x8 b, f32x4 c) {
    return __builtin_amdgcn_mfma_f32_16x16x32_bf16(
        __builtin_bit_cast(bf16x8, a), __builtin_bit_cast(bf16x8, b), c, 0, 0, 0);
}

#define GLDS16(gp, lp)                                                          \
    __builtin_amdgcn_global_load_lds(                                           \
        (const __attribute__((address_space(1))) void*)(gp),                    \
        (__attribute__((address_space(3))) void*)(lp), 16, 0, 0)

// ---------------- fp32 -> bf16 convert (x | Wqkv | fc_w fused) ---------------
__global__ __launch_bounds__(256) void cvt3_kernel(const float* __restrict__ s0,
                                                   const float* __restrict__ s1,
                                                   const float* __restrict__ s2,
                                                   u16* __restrict__ d0,
                                                   u16* __restrict__ d1,
                                                   u16* __restrict__ d2) {
    int i = (blockIdx.x * 256 + threadIdx.x) * 4;   // block-uniform ranges
    const float* src; u16* dst;
    if (i < 4194304)       { src = s0;           dst = d0;           }
    else if (i < 8388608)  { src = s1 - 4194304; dst = d1 - 4194304; }
    else                   { src = s2 - 8388608; dst = d2 - 8388608; }
    float4 f = *(const float4*)(src + i);
    u16x4 o = { f2b(f.x), f2b(f.y), f2b(f.z), f2b(f.w) };
    *(u16x4*)(dst + i) = o;
}

// ---------------- NT bf16 GEMM, K=1024, double-buffered LDS ------------------
// MODE 0 (MT=128), grid (32,32): bx<24 -> q/k1/k2 with SWAPPED operands
// (A=W-tile, B=x-tile) so D-rows run along d; frag chunk [bh][tok16][kh]
// [tok&15][d&31] gets per-lane 4-consecutive-d -> packed dwordx2 stores.
// bx>=24 -> v, original orientation, chunk [bh][d>>4][tok>>5][(d&15)][tok&31].
// MODE 1 (MT=64): Cf[m][n] = acc + bias[n]  (fp32, ld 1024)
template <int MT, int MODE>
__global__ __launch_bounds__(256) void gemm_bt(
    const u16* __restrict__ A, const u16* __restrict__ Bw,
    u16* __restrict__ Qf, u16* __restrict__ K1f,
    u16* __restrict__ K2f, u16* __restrict__ Vf,
    float* __restrict__ Cf, const float* __restrict__ biasp)
{
    constexpr int K = 1024;
    constexpr int MF = MT / 32;            // A-frags per wave (4 or 2)
    __shared__ u16 As[2][MT * 32];
    __shared__ u16 Bs[2][128 * 32];
    const int t = threadIdx.x;
    const int lane = t & 63;
    const int w = t >> 6;
    const int wm = w >> 1, wn = w & 1;
    const int lr = lane & 15, quad = lane >> 4;
    const int tileM = blockIdx.y * MT, tileN = blockIdx.x * 128;

    f32x4 acc[MF][4] = {};

    const u16* Ag = A + (size_t)(tileM + (t >> 2)) * K + (t & 3) * 8;
    const u16* Bg = Bw + (size_t)(tileN + (t >> 2)) * K + (t & 3) * 8;

    // operand swap for q/k1/k2 blocks (block-uniform)
    const bool swp = (MODE == 0) && (blockIdx.x < 24);
    const u16* Afb = swp ? &Bs[0][0] : &As[0][0];
    const u16* Bfb = swp ? &As[0][0] : &Bs[0][0];
    const int AfS = swp ? 128 * 32 : MT * 32;
    const int BfS = swp ? MT * 32 : 128 * 32;

#define STAGE(kk, bufi)                                                         \
    do {                                                                        \
        GLDS16(Ag + (kk), &As[bufi][t * 8]);                                    \
        if (MT == 128) GLDS16(Ag + (kk) + 64 * K, &As[bufi][t * 8 + 2048]);     \
        GLDS16(Bg + (kk), &Bs[bufi][t * 8]);                                    \
        GLDS16(Bg + (kk) + 64 * K, &Bs[bufi][t * 8 + 2048]);                    \
    } while (0)

    STAGE(0, 0);
    __syncthreads();

#pragma unroll 2
    for (int kk = 0; kk < K; kk += 32) {
        const int cur = (kk >> 5) & 1;
        if (kk + 32 < K) STAGE(kk + 32, cur ^ 1);   // prefetch next tile

        u16x8 af[MF], bf[4];
#pragma unroll
        for (int i = 0; i < MF; ++i)
            af[i] = *(const u16x8*)(Afb + cur * AfS + (wm * (MT / 2) + i * 16 + lr) * 32 + quad * 8);
#pragma unroll
        for (int i = 0; i < 4; ++i)
            bf[i] = *(const u16x8*)(Bfb + cur * BfS + (wn * 64 + i * 16 + lr) * 32 + quad * 8);
#pragma unroll
        for (int mi = 0; mi < MF; ++mi)
#pragma unroll
            for (int ni = 0; ni < 4; ++ni)
                acc[mi][ni] = mfma16(af[mi], bf[ni], acc[mi][ni]);

        __syncthreads();   // drains prefetch vmcnt + protects buffer reuse
    }
#undef STAGE

    if (MODE == 0) {
        if (swp) {
            // q/k1/k2: D-row = feature f = (bx&7)*128 + wm*64 + mi*16 + quad*4 + r
            //          D-col = token    = (by)*128 + wn*64 + ni*16 + lr
            const int kvi = blockIdx.x >> 3;
            const int h = ((blockIdx.x & 7) << 1) + wm;          // wave-uniform
            const int bh = ((blockIdx.y >> 2) << 4) + h;
            const int t16b = ((blockIdx.y & 3) << 3) + wn * 4;
            u16* bp = (kvi == 0 ? Qf : (kvi == 1 ? K1f : K2f))
                    + ((size_t)(bh * 32 + t16b) * 2) * 512 + lr * 32 + quad * 4;
#pragma unroll
            for (int mi = 0; mi < MF; ++mi)
#pragma unroll
                for (int ni = 0; ni < 4; ++ni) {
                    uint2 v;
                    v.x = pk2(acc[mi][ni][0], acc[mi][ni][1]);
                    v.y = pk2(acc[mi][ni][2], acc[mi][ni][3]);
                    *(uint2*)(bp + ni * 1024 + (mi >> 1) * 512 + (mi & 1) * 16) = v;
                }
        } else {
            // v: D-row = token = by*128 + wm*64 + mi*16 + quad*4 + r
            //    D-col -> d = ni*16 + lr, h = (bx-24)*2 + wn
            const int h = ((blockIdx.x - 24) << 1) + wn;
            const int bh = ((blockIdx.y >> 2) << 4) + h;
            const int t5b = ((blockIdx.y & 3) << 2) + wm * 2;
            u16* bp = Vf + ((size_t)(bh * 4) * 16 + t5b) * 512 + lr * 32 + quad * 4;
#pragma unroll
            for (int mi = 0; mi < MF; ++mi)
#pragma unroll
                for (int ni = 0; ni < 4; ++ni) {
                    uint2 v;
                    v.x = pk2(acc[mi][ni][0], acc[mi][ni][1]);
                    v.y = pk2(acc[mi][ni][2], acc[mi][ni][3]);
                    *(uint2*)(bp + ni * 8192 + (mi >> 1) * 512 + (mi & 1) * 16) = v;
                }
        }
    } else {
#pragma unroll
        for (int mi = 0; mi < MF; ++mi)
#pragma unroll
            for (int ni = 0; ni < 4; ++ni) {
                int n = tileN + wn * 64 + ni * 16 + lr;
                float bv = biasp[n];
#pragma unroll
                for (int r = 0; r < 4; ++r) {
                    int m = tileM + wm * (MT / 2) + mi * 16 + quad * 4 + r;
                    Cf[(size_t)m * 1024 + n] = acc[mi][ni][r] + bv;
                }
            }
    }
}

// ---------------- attention: barrier-free, register-direct frag loads --------
// Grid 512 linear: bh = blk&127 (same-bh blocks stride 128 = 0 mod 8 -> same
// XCD for L2 locality), qt = blk>>7 (0..3). Wave w owns 32 q-rows.
// Frag chunks in global: q/k1/k2 [tok&15][d&31], v [d&15][tok&31]; lane's
// 16B frag sits at chunkbase + lr*32 + quad*8 (wave union = contiguous 1KB).
__global__ __launch_bounds__(256) void attn_kernel(
    const u16* __restrict__ qfm, const u16* __restrict__ k1fm,
    const u16* __restrict__ k2fm, const u16* __restrict__ vfm,
    const int* __restrict__ maskp, const int* __restrict__ qmaskp,
    const float* __restrict__ shiftp, const float* __restrict__ biasp,
    u16* __restrict__ ao)
{
    __shared__ u16 Pw[4][2][512];        // per-wave, per-row-group swizzled P

    const int bh = blockIdx.x & 127, qt = blockIdx.x >> 7;
    const int b = bh >> 4, h = bh & 15;
    const int t = threadIdx.x, lane = t & 63, w = t >> 6;
    const int lr = lane & 15, quad = lane >> 4;
    const float shiftv = shiftp[0], biasv = biasp[0];

    const int qbase = qt * 128 + w * 32;    // wave's first q row
    const int m16 = qbase >> 4;             // first 16-row group index
    const int loff = lr * 32 + quad * 8;    // lane's intra-chunk frag offset

    // Q A-frags: [g][kh]
    const u16* qb = qfm + ((size_t)(bh * 32 + m16) * 2) * 512 + loff;
    u16x8 qa[2][2];
    qa[0][0] = *(const u16x8*)(qb);
    qa[0][1] = *(const u16x8*)(qb + 512);
    qa[1][0] = *(const u16x8*)(qb + 1024);
    qa[1][1] = *(const u16x8*)(qb + 1536);

    int qmr[2][4]; float rowf[2][4];
#pragma unroll
    for (int g = 0; g < 2; ++g)
#pragma unroll
        for (int r = 0; r < 4; ++r) {
            int m = qbase + g * 16 + quad * 4 + r;
            qmr[g][r] = qmaskp[b * 512 + m];
            rowf[g][r] = (float)m;
        }

    f32x4 o[2][4] = {};
    float lsum[2][4] = {};

    u16* pb[2] = { &Pw[w][0][0], &Pw[w][1][0] };
    const int wa0 = quad * 128 + (((lr >> 3) ^ quad) * 8) + (lr & 7);
    const int wa1 = quad * 128 + (((2 | (lr >> 3)) ^ quad) * 8) + (lr & 7);
    const int ra = lr * 32 + ((quad ^ (lr >> 2)) * 8);

    const u16* k1b = k1fm + (size_t)bh * 32768 + loff;
    const u16* k2b = k2fm + (size_t)bh * 32768 + loff;
    const u16* vb  = vfm  + (size_t)bh * 32768 + loff;
    const int* qmb = qmaskp + b * 512;
    const int* kmb = maskp + b * 512;

#pragma unroll 2
    for (int cc = 0; cc < 16; ++cc) {
        const u16* kc1 = k1b + cc * 2048;
        const u16* kc2 = k2b + cc * 2048;
        u16x8 k1f_[2][2], k2f_[2][2];
        k1f_[0][0] = *(const u16x8*)(kc1);
        k1f_[0][1] = *(const u16x8*)(kc1 + 512);
        k1f_[1][0] = *(const u16x8*)(kc1 + 1024);
        k1f_[1][1] = *(const u16x8*)(kc1 + 1536);
        k2f_[0][0] = *(const u16x8*)(kc2);
        k2f_[0][1] = *(const u16x8*)(kc2 + 512);
        k2f_[1][0] = *(const u16x8*)(kc2 + 1024);
        k2f_[1][1] = *(const u16x8*)(kc2 + 1536);
        u16x8 vf_[4];
#pragma unroll
        for (int ot = 0; ot < 4; ++ot)
            vf_[ot] = *(const u16x8*)(vb + (size_t)(ot * 16 + cc) * 512);

        f32x4 z = {0.f, 0.f, 0.f, 0.f};
        f32x4 s1[2][2], s2[2][2];
#pragma unroll
        for (int g = 0; g < 2; ++g)
#pragma unroll
            for (int tg = 0; tg < 2; ++tg) {
                s1[g][tg] = mfma16(qa[g][1], k1f_[tg][1], mfma16(qa[g][0], k1f_[tg][0], z));
                s2[g][tg] = mfma16(qa[g][1], k2f_[tg][1], mfma16(qa[g][0], k2f_[tg][0], z));
            }

        const int col0 = cc * 32 + lr, col1 = col0 + 16;
        const int qmc0 = qmb[col0], qmc1 = qmb[col1];
        const float ka0 = (kmb[col0] ? 0.f : -1e30f) - 10.0f;   // mask + max-shift
        const float ka1 = (kmb[col1] ? 0.f : -1e30f) - 10.0f;
        const float colf0 = (float)col0, colf1 = (float)col1;

#pragma unroll
        for (int g = 0; g < 2; ++g) {
#pragma unroll
            for (int r = 0; r < 4; ++r) {
                float d0 = rowf[g][r] - colf0;
                float d1 = rowf[g][r] - colf1;
                float sel0 = (qmr[g][r] == qmc0) ? s1[g][0][r] : s2[g][0][r];
                float sel1 = (qmr[g][r] == qmc1) ? s1[g][1][r] : s2[g][1][r];
                float v0 = fmaf(sel0, 0.125f, -fmaf(shiftv * d0, d0, biasv)) + ka0;
                float v1 = fmaf(sel1, 0.125f, -fmaf(shiftv * d1, d1, biasv)) + ka1;
                float p0 = __expf(v0);
                float p1 = __expf(v1);
                lsum[g][r] += p0 + p1;
                pb[g][wa0 + r * 32] = f2b(p0);
                pb[g][wa1 + r * 32] = f2b(p1);
            }
        }
#pragma unroll
        for (int g = 0; g < 2; ++g) {
            u16x8 af = *(const u16x8*)(pb[g] + ra);   // same-wave RAW; lgkmcnt
#pragma unroll
            for (int ot = 0; ot < 4; ++ot)
                o[g][ot] = mfma16(af, vf_[ot], o[g][ot]);
        }
    }

    // epilogue: finish row sums across the 16 lr lanes, normalize, store
#pragma unroll
    for (int g = 0; g < 2; ++g)
#pragma unroll
        for (int r = 0; r < 4; ++r) {
            float s = lsum[g][r];
#pragma unroll
            for (int m = 1; m < 16; m <<= 1) s += __shfl_xor(s, m);
            float inv = 1.0f / s;
            int grow = b * 512 + qbase + g * 16 + quad * 4 + r;
            u16* orow = ao + (size_t)grow * 1024 + h * 64 + lr;
            orow[0]  = f2b(o[g][0][r] * inv);
            orow[16] = f2b(o[g][1][r] * inv);
            orow[32] = f2b(o[g][2][r] * inv);
            orow[48] = f2b(o[g][3][r] * inv);
        }
}

extern "C" void kernel_launch(void* const* d_in, const int* in_sizes, int n_in,
                              void* d_out, int out_size, void* d_ws, size_t ws_size,
                              hipStream_t stream) {
    (void)in_sizes; (void)n_in; (void)out_size; (void)ws_size;
    const float* x      = (const float*)d_in[0];
    const int*   maskp  = (const int*)d_in[1];
    const int*   qmaskp = (const int*)d_in[2];
    const float* Wqkv   = (const float*)d_in[3];
    const float* fc_w   = (const float*)d_in[4];
    const float* fc_b   = (const float*)d_in[5];
    const float* shiftp = (const float*)d_in[6];
    const float* biasp  = (const float*)d_in[7];
    float* out = (float*)d_out;

    char* ws = (char*)d_ws;
    u16* xb   = (u16*)(ws);                      //  8 MB: x bf16 [4096,1024]
    u16* wb   = (u16*)(ws + (8u << 20));         //  8 MB: Wqkv bf16 [4096,1024]
    u16* fwb  = (u16*)(ws + (16u << 20));        //  2 MB: fc_w bf16 [1024,1024]
    u16* qfm  = (u16*)(ws + (18u << 20));        //  8 MB: q frag-major
    u16* k1fm = (u16*)(ws + (26u << 20));        //  8 MB: k1 frag-major
    u16* k2fm = (u16*)(ws + (34u << 20));        //  8 MB: k2 frag-major
    u16* vfm  = (u16*)(ws + (42u << 20));        //  8 MB: v frag-major
    u16* aob  = (u16*)(ws + (50u << 20));        //  8 MB: attn out bf16 [4096,1024]

    cvt3_kernel<<<9216, 256, 0, stream>>>(x, Wqkv, fc_w, xb, wb, fwb);
    gemm_bt<128, 0><<<dim3(32, 32), 256, 0, stream>>>(xb, wb, qfm, k1fm, k2fm, vfm,
                                                      nullptr, nullptr);
    attn_kernel<<<512, 256, 0, stream>>>(qfm, k1fm, k2fm, vfm, maskp, qmaskp,
                                         shiftp, biasp, aob);
    gemm_bt<64, 1><<<dim3(8, 64), 256, 0, stream>>>(aob, fwb, nullptr, nullptr,
                                                    nullptr, nullptr, out, fc_b);
}